// Round 3
// baseline (510.483 us; speedup 1.0000x reference)
//
#include <hip/hip_runtime.h>

// MultiheadFeedForward: x[4,4096,2048] fp32; per-head FFN (H=16, dh=128, ff=512)
//   h = relu(x_h @ W1[h] + b1[h]);  out_h = h @ W2[h] + b2[h]
// FP32 global I/O; bf16 MFMA compute. Fused two-GEMM kernel, FF in 4 chunks of
// 128. R3: occupancy fix — only Hs lives in LDS (34.8 KB); W1/W2 fragments are
// loaded straight from global (L2-hot), grid transposed for per-XCD weight
// locality; launch_bounds(256,3) -> 3 blocks/CU (12 waves) vs R2's 1 block.

typedef __attribute__((ext_vector_type(8))) short short8;
typedef __attribute__((ext_vector_type(4))) short short4v;
typedef __attribute__((ext_vector_type(4))) float f32x4;

#define NHEADS 16
#define DHEAD  128
#define NFF    512
#define DMODEL 2048
#define NTOK   16384
#define MT     128   // token tile per block
#define FC     128   // ff chunk
#define LPAD   136   // LDS row stride (bf16): 272B = odd*16B -> only free 2-way aliasing

__device__ __forceinline__ short f2bf(float f) {
    unsigned u = __builtin_bit_cast(unsigned, f);
    u += 0x7FFFu + ((u >> 16) & 1u);   // RNE
    return (short)(u >> 16);
}

// Batched 32x32-tiled transpose + fp32->bf16: dst[h][c][r] = bf16(src[h][r][c])
__global__ __launch_bounds__(256) void transpose_k(const float* __restrict__ src,
                                                   short* __restrict__ dst,
                                                   int R, int C) {
    __shared__ short tile[32][33];
    const int h = blockIdx.z;
    const float* s = src + (size_t)h * R * C;
    short* d = dst + (size_t)h * R * C;
    const int c0 = blockIdx.x * 32, r0 = blockIdx.y * 32;
    const int t = threadIdx.x;
    for (int p = 0; p < 4; ++p) {
        int v = p * 256 + t;
        int r = v >> 5, cc = v & 31;
        tile[r][cc] = f2bf(s[(size_t)(r0 + r) * C + (c0 + cc)]);
    }
    __syncthreads();
    for (int p = 0; p < 4; ++p) {
        int v = p * 256 + t;
        int cc = v >> 5, r = v & 31;
        d[(size_t)(c0 + cc) * R + (r0 + r)] = tile[r][cc];
    }
}

// Grid: (mtile=128, head=16); block 256 (4 waves).
// GEMM1: D1[f][m] = W1T(A) x X(B); GEMM2: D2[d][m] = W2T(A) x H(B).
// 16x16x32 bf16 MFMA. A-frag: lane holds A[m'=lane&15][k=quad*8+j].
// B-frag: lane holds B[k=quad*8+j][n=lane&15]. C/D: col=lane&15, row=quad*4+reg.
__global__ __launch_bounds__(256, 3) void ffn_main(
        const float* __restrict__ x,    // [NTOK][DMODEL] fp32
        const short* __restrict__ w1t,  // [H][NFF][DHEAD] bf16 (f, d)
        const float* __restrict__ b1,   // [H][NFF] fp32
        const short* __restrict__ w2t,  // [H][DHEAD][NFF] bf16 (d, f)
        const float* __restrict__ b2,   // [H][DHEAD] fp32
        float* __restrict__ out) {      // [NTOK][DMODEL] fp32
    __shared__ short Hs[MT][LPAD];     // [m][f_local]  34.8 KB — the only LDS

    const int m0   = blockIdx.x * MT;
    const int h    = blockIdx.y;
    const int tid  = threadIdx.x;
    const int lane = tid & 63;
    const int wave = tid >> 6;
    const int quad = lane >> 4;
    const int l16  = lane & 15;
    const int wf   = wave >> 1;  // f/d half (0/1) of 128
    const int wm   = wave & 1;   // m half (0/1) of 128

    // X as GEMM1 B-operand: lane holds B[k=d][n=m] = x[m][d]. K=128 fixed
    // across chunks -> load fp32 once, keep bf16 in regs (64 VGPRs).
    short8 xf[4][4];  // [mi][kk]
    {
        const float* xb = x + (size_t)(m0 + wm * 64) * DMODEL + h * DHEAD;
        for (int mi = 0; mi < 4; ++mi)
            for (int kk = 0; kk < 4; ++kk) {
                const float* p = xb + (size_t)(mi * 16 + l16) * DMODEL + kk * 32 + quad * 8;
                f32x4 a = *(const f32x4*)(p);
                f32x4 b = *(const f32x4*)(p + 4);
                short8 v;
                v[0] = f2bf(a[0]); v[1] = f2bf(a[1]); v[2] = f2bf(a[2]); v[3] = f2bf(a[3]);
                v[4] = f2bf(b[0]); v[5] = f2bf(b[1]); v[6] = f2bf(b[2]); v[7] = f2bf(b[3]);
                xf[mi][kk] = v;
            }
    }

    f32x4 acc2[4][4];  // [di][mi], persistent across chunks
    for (int di = 0; di < 4; ++di)
        for (int mi = 0; mi < 4; ++mi)
            acc2[di][mi] = (f32x4){0.f, 0.f, 0.f, 0.f};

    // Per-lane weight base pointers (A-frags read 16B at [row=..+l16][col=..+quad*8])
    const short* w1b = w1t + (size_t)h * NFF * DHEAD + (size_t)(wf * 64 + l16) * DHEAD + quad * 8;
    const short* w2b = w2t + (size_t)h * DHEAD * NFF + (size_t)(wf * 64 + l16) * NFF + quad * 8;

    for (int c = 0; c < 4; ++c) {
        // ---- GEMM1: acc1[fi][mi] over k=d (4 steps of 32); W1 frags from global (L2)
        f32x4 acc1[4][4];
        for (int fi = 0; fi < 4; ++fi)
            for (int mi = 0; mi < 4; ++mi)
                acc1[fi][mi] = (f32x4){0.f, 0.f, 0.f, 0.f};
        for (int kk = 0; kk < 4; ++kk) {
            short8 af[4];
            for (int fi = 0; fi < 4; ++fi)
                af[fi] = *(const short8*)(w1b + (size_t)(c * FC + fi * 16) * DHEAD + kk * 32);
            for (int fi = 0; fi < 4; ++fi)
                for (int mi = 0; mi < 4; ++mi)
                    acc1[fi][mi] = __builtin_amdgcn_mfma_f32_16x16x32_bf16(
                        af[fi], xf[mi][kk], acc1[fi][mi], 0, 0, 0);
        }

        // ---- bias + relu -> Hs[m][f] bf16 (packed 8B writes)
        for (int fi = 0; fi < 4; ++fi) {
            const float* pb = b1 + h * NFF + c * FC + wf * 64 + fi * 16 + quad * 4;
            float bb[4] = {pb[0], pb[1], pb[2], pb[3]};
            for (int mi = 0; mi < 4; ++mi) {
                int m = wm * 64 + mi * 16 + l16;
                short4v hv;
                for (int r = 0; r < 4; ++r)
                    hv[r] = f2bf(fmaxf(acc1[fi][mi][r] + bb[r], 0.f));
                *(short4v*)&Hs[m][wf * 64 + fi * 16 + quad * 4] = hv;
            }
        }
        __syncthreads();   // Hs complete before GEMM2 reads

        // ---- GEMM2: acc2 += W2T(A) x H(B) over k=f (4 steps of 32); W2 from global
        for (int kk = 0; kk < 4; ++kk) {
            short8 wfr[4], hfr[4];
            for (int di = 0; di < 4; ++di)
                wfr[di] = *(const short8*)(w2b + (size_t)(di * 16) * NFF + c * FC + kk * 32);
            for (int mi = 0; mi < 4; ++mi)
                hfr[mi] = *(const short8*)&Hs[wm * 64 + mi * 16 + l16][kk * 32 + quad * 8];
            for (int di = 0; di < 4; ++di)
                for (int mi = 0; mi < 4; ++mi)
                    acc2[di][mi] = __builtin_amdgcn_mfma_f32_16x16x32_bf16(
                        wfr[di], hfr[mi], acc2[di][mi], 0, 0, 0);
        }
        __syncthreads();   // GEMM2 reads done before next chunk overwrites Hs
    }

    // ---- epilogue: out[m][h*128+d] fp32, 16B stores (regs = consecutive d)
    for (int di = 0; di < 4; ++di) {
        const float* pb = b2 + h * DHEAD + wf * 64 + di * 16 + quad * 4;
        float bb[4] = {pb[0], pb[1], pb[2], pb[3]};
        for (int mi = 0; mi < 4; ++mi) {
            int m = m0 + wm * 64 + mi * 16 + l16;
            f32x4 ov;
            for (int r = 0; r < 4; ++r)
                ov[r] = acc2[di][mi][r] + bb[r];
            *(f32x4*)(out + (size_t)m * DMODEL + h * DHEAD + wf * 64 + di * 16 + quad * 4) = ov;
        }
    }
}

extern "C" void kernel_launch(void* const* d_in, const int* in_sizes, int n_in,
                              void* d_out, int out_size, void* d_ws, size_t ws_size,
                              hipStream_t stream) {
    const float* x  = (const float*)d_in[0];
    const float* W1 = (const float*)d_in[1];
    const float* b1 = (const float*)d_in[2];
    const float* W2 = (const float*)d_in[3];
    const float* b2 = (const float*)d_in[4];
    float* out = (float*)d_out;

    short* w1t = (short*)d_ws;                                  // [16][512][128] bf16
    short* w2t = (short*)d_ws + (size_t)NHEADS * NFF * DHEAD;   // [16][128][512] bf16

    // W1 [h][128][512] fp32 -> w1t [h][512][128] bf16
    transpose_k<<<dim3(NFF / 32, DHEAD / 32, NHEADS), 256, 0, stream>>>(W1, w1t, DHEAD, NFF);
    // W2 [h][512][128] fp32 -> w2t [h][128][512] bf16
    transpose_k<<<dim3(DHEAD / 32, NFF / 32, NHEADS), 256, 0, stream>>>(W2, w2t, NFF, DHEAD);

    ffn_main<<<dim3(NTOK / MT, NHEADS), 256, 0, stream>>>(x, w1t, b1, w2t, b2, out);
}

// Round 4
// 445.819 us; speedup vs baseline: 1.1450x; 1.1450x over previous
//
#include <hip/hip_runtime.h>

// MultiheadFeedForward: x[4,4096,2048] fp32; per-head FFN (H=16, dh=128, ff=512)
//   h = relu(x_h @ W1[h] + b1[h]);  out_h = h @ W2[h] + b2[h]
// FP32 global I/O; bf16 MFMA compute. Fused two-GEMM kernel, FF in 4 chunks of
// 128, Hs (34.8 KB) is the only LDS. W1/W2 fragments read from global (L2-hot).
// R4: launch_bounds(256,1) — R3's (256,3) made the allocator spill xf/acc
// (VGPR 84 < live 96+) -> 700 MB scratch traffic. R2 proved 160 VGPR fits
// spill-free, and 160 VGPR alone gives 12 waves/CU = 3 blocks/CU.

typedef __attribute__((ext_vector_type(8))) short short8;
typedef __attribute__((ext_vector_type(4))) short short4v;
typedef __attribute__((ext_vector_type(2))) short short2v;
typedef __attribute__((ext_vector_type(4))) float f32x4;

#define NHEADS 16
#define DHEAD  128
#define NFF    512
#define DMODEL 2048
#define NTOK   16384
#define MT     128   // token tile per block
#define FC     128   // ff chunk
#define LPAD   136   // LDS row stride (bf16): 272B = odd*16B -> only free 2-way aliasing

__device__ __forceinline__ short f2bf(float f) {
    unsigned u = __builtin_bit_cast(unsigned, f);
    u += 0x7FFFu + ((u >> 16) & 1u);   // RNE
    return (short)(u >> 16);
}

// Fused transpose+convert for BOTH weight tensors in one launch.
// z = h*2 + which; which=0: W1[h] 128x512 -> w1t[h] 512x128
//                  which=1: W2[h] 512x128 -> w2t[h] 128x512
__global__ __launch_bounds__(256) void transpose_both(
        const float* __restrict__ W1, const float* __restrict__ W2,
        short* __restrict__ w1t, short* __restrict__ w2t) {
    __shared__ short tile[32][33];
    const int z = blockIdx.z;
    const int which = z & 1, h = z >> 1;
    const int R = which ? NFF : DHEAD;      // src rows
    const int C = which ? DHEAD : NFF;      // src cols
    const float* s = (which ? W2 : W1) + (size_t)h * DHEAD * NFF;
    short* d = (which ? w2t : w1t) + (size_t)h * DHEAD * NFF;
    const int t0 = blockIdx.x + 8 * blockIdx.y;  // 0..63 tile id
    const int ctiles = C / 32;
    const int c0 = (t0 % ctiles) * 32, r0 = (t0 / ctiles) * 32;
    const int t = threadIdx.x;
    for (int p = 0; p < 4; ++p) {
        int v = p * 256 + t;
        int r = v >> 5, cc = v & 31;
        tile[r][cc] = f2bf(s[(size_t)(r0 + r) * C + (c0 + cc)]);
    }
    __syncthreads();
    // store: lane -> 2 consecutive r at fixed cc; 16 lanes = 64B contiguous run
    for (int it = 0; it < 2; ++it) {
        int idx = it * 256 + t;
        int l16 = idx & 15, cc = idx >> 4;   // cc 0..31
        int r = l16 * 2;
        short2v v2; v2[0] = tile[r][cc]; v2[1] = tile[r + 1][cc];
        *(short2v*)&d[(size_t)(c0 + cc) * R + r0 + r] = v2;
    }
}

// Grid: (mtile=128, head=16); block 256 (4 waves).
// GEMM1: D1[f][m] = W1T(A) x X(B); GEMM2: D2[d][m] = W2T(A) x H(B).
// 16x16x32 bf16 MFMA. A-frag: lane holds A[m'=lane&15][k=quad*8+j].
// B-frag: lane holds B[k=quad*8+j][n=lane&15]. C/D: col=lane&15, row=quad*4+reg.
__global__ __launch_bounds__(256, 1) void ffn_main(
        const float* __restrict__ x,    // [NTOK][DMODEL] fp32
        const short* __restrict__ w1t,  // [H][NFF][DHEAD] bf16 (f, d)
        const float* __restrict__ b1,   // [H][NFF] fp32
        const short* __restrict__ w2t,  // [H][DHEAD][NFF] bf16 (d, f)
        const float* __restrict__ b2,   // [H][DHEAD] fp32
        float* __restrict__ out) {      // [NTOK][DMODEL] fp32
    __shared__ short Hs[MT][LPAD];     // [m][f_local]  34.8 KB — the only LDS

    const int m0   = blockIdx.x * MT;
    const int h    = blockIdx.y;
    const int tid  = threadIdx.x;
    const int lane = tid & 63;
    const int wave = tid >> 6;
    const int quad = lane >> 4;
    const int l16  = lane & 15;
    const int wf   = wave >> 1;  // f/d half (0/1) of 128
    const int wm   = wave & 1;   // m half (0/1) of 128

    // X as GEMM1 B-operand: lane holds B[k=d][n=m] = x[m][d]. K=128 fixed
    // across chunks -> load fp32 once, keep bf16 in regs (64 VGPRs).
    short8 xf[4][4];  // [mi][kk]
    {
        const float* xb = x + (size_t)(m0 + wm * 64) * DMODEL + h * DHEAD;
        for (int mi = 0; mi < 4; ++mi)
            for (int kk = 0; kk < 4; ++kk) {
                const float* p = xb + (size_t)(mi * 16 + l16) * DMODEL + kk * 32 + quad * 8;
                f32x4 a = *(const f32x4*)(p);
                f32x4 b = *(const f32x4*)(p + 4);
                short8 v;
                v[0] = f2bf(a[0]); v[1] = f2bf(a[1]); v[2] = f2bf(a[2]); v[3] = f2bf(a[3]);
                v[4] = f2bf(b[0]); v[5] = f2bf(b[1]); v[6] = f2bf(b[2]); v[7] = f2bf(b[3]);
                xf[mi][kk] = v;
            }
    }

    f32x4 acc2[4][4];  // [di][mi], persistent across chunks
    for (int di = 0; di < 4; ++di)
        for (int mi = 0; mi < 4; ++mi)
            acc2[di][mi] = (f32x4){0.f, 0.f, 0.f, 0.f};

    // Per-lane weight base pointers (A-frags read 16B at [row=..+l16][col=..+quad*8])
    const short* w1b = w1t + (size_t)h * NFF * DHEAD + (size_t)(wf * 64 + l16) * DHEAD + quad * 8;
    const short* w2b = w2t + (size_t)h * DHEAD * NFF + (size_t)(wf * 64 + l16) * NFF + quad * 8;

    for (int c = 0; c < 4; ++c) {
        // ---- GEMM1: acc1[fi][mi] over k=d (4 steps of 32); W1 frags from global (L2)
        f32x4 acc1[4][4];
        for (int fi = 0; fi < 4; ++fi)
            for (int mi = 0; mi < 4; ++mi)
                acc1[fi][mi] = (f32x4){0.f, 0.f, 0.f, 0.f};
        for (int kk = 0; kk < 4; ++kk) {
            short8 af[4];
            for (int fi = 0; fi < 4; ++fi)
                af[fi] = *(const short8*)(w1b + (size_t)(c * FC + fi * 16) * DHEAD + kk * 32);
            for (int fi = 0; fi < 4; ++fi)
                for (int mi = 0; mi < 4; ++mi)
                    acc1[fi][mi] = __builtin_amdgcn_mfma_f32_16x16x32_bf16(
                        af[fi], xf[mi][kk], acc1[fi][mi], 0, 0, 0);
        }

        // ---- bias + relu -> Hs[m][f] bf16 (packed 8B writes)
        for (int fi = 0; fi < 4; ++fi) {
            f32x4 bb = *(const f32x4*)(b1 + h * NFF + c * FC + wf * 64 + fi * 16 + quad * 4);
            for (int mi = 0; mi < 4; ++mi) {
                int m = wm * 64 + mi * 16 + l16;
                short4v hv;
                for (int r = 0; r < 4; ++r)
                    hv[r] = f2bf(fmaxf(acc1[fi][mi][r] + bb[r], 0.f));
                *(short4v*)&Hs[m][wf * 64 + fi * 16 + quad * 4] = hv;
            }
        }
        __syncthreads();   // Hs complete before GEMM2 reads

        // ---- GEMM2: acc2 += W2T(A) x H(B) over k=f (4 steps of 32); W2 from global
        for (int kk = 0; kk < 4; ++kk) {
            short8 wfr[4], hfr[4];
            for (int di = 0; di < 4; ++di)
                wfr[di] = *(const short8*)(w2b + (size_t)(di * 16) * NFF + c * FC + kk * 32);
            for (int mi = 0; mi < 4; ++mi)
                hfr[mi] = *(const short8*)&Hs[wm * 64 + mi * 16 + l16][kk * 32 + quad * 8];
            for (int di = 0; di < 4; ++di)
                for (int mi = 0; mi < 4; ++mi)
                    acc2[di][mi] = __builtin_amdgcn_mfma_f32_16x16x32_bf16(
                        wfr[di], hfr[mi], acc2[di][mi], 0, 0, 0);
        }
        __syncthreads();   // GEMM2 reads done before next chunk overwrites Hs
    }

    // ---- epilogue: out[m][h*128+d] fp32, 16B stores (regs = consecutive d)
    for (int di = 0; di < 4; ++di) {
        f32x4 bb = *(const f32x4*)(b2 + h * DHEAD + wf * 64 + di * 16 + quad * 4);
        for (int mi = 0; mi < 4; ++mi) {
            int m = m0 + wm * 64 + mi * 16 + l16;
            f32x4 ov;
            for (int r = 0; r < 4; ++r)
                ov[r] = acc2[di][mi][r] + bb[r];
            *(f32x4*)(out + (size_t)m * DMODEL + h * DHEAD + wf * 64 + di * 16 + quad * 4) = ov;
        }
    }
}

extern "C" void kernel_launch(void* const* d_in, const int* in_sizes, int n_in,
                              void* d_out, int out_size, void* d_ws, size_t ws_size,
                              hipStream_t stream) {
    const float* x  = (const float*)d_in[0];
    const float* W1 = (const float*)d_in[1];
    const float* b1 = (const float*)d_in[2];
    const float* W2 = (const float*)d_in[3];
    const float* b2 = (const float*)d_in[4];
    float* out = (float*)d_out;

    short* w1t = (short*)d_ws;                                  // [16][512][128] bf16
    short* w2t = (short*)d_ws + (size_t)NHEADS * NFF * DHEAD;   // [16][128][512] bf16

    // Both weight transposes (fp32 -> bf16, [r][c] -> [c][r]) in one launch.
    transpose_both<<<dim3(8, 8, 2 * NHEADS), 256, 0, stream>>>(W1, W2, w1t, w2t);

    ffn_main<<<dim3(NTOK / MT, NHEADS), 256, 0, stream>>>(x, w1t, b1, w2t, b2, out);
}